// Round 18
// baseline (47.444 us; speedup 1.0000x reference)
//
#include <hip/hip_runtime.h>
#include <hip/hip_bf16.h>

// Problem constants
#define BB 8
#define TT 2048
#define CC 1024
#define HH 64

typedef float f32x4 __attribute__((ext_vector_type(4)));
typedef float f32x16 __attribute__((ext_vector_type(16)));
typedef short s16x8 __attribute__((ext_vector_type(8)));   // 8 bf16 in 4 VGPRs

// fp32 -> bf16 (RNE), pure bit math
static __device__ __forceinline__ unsigned short f2bf(float f) {
    unsigned int u = __float_as_uint(f);
    u = (u + 0x7FFFu + ((u >> 16) & 1u)) >> 16;
    return (unsigned short)u;
}

// pack two f32 -> 2 bf16 in one dword (RNE); dst.lo = src0, dst.hi = src1
static __device__ __forceinline__ unsigned cvt_pk_bf16(float lo, float hi) {
    unsigned r;
    asm("v_cvt_pk_bf16_f32 %0, %1, %2" : "=v"(r) : "v"(lo), "v"(hi));
    return r;
}

// ---------------------------------------------------------------------------
// Kernel 0: pack Wq|Wk|Wv [1024][64] fp32 into MFMA B-fragment order, bf16.
// ---------------------------------------------------------------------------
__global__ __launch_bounds__(256) void wt_kernel(
    const float* __restrict__ Wq, const float* __restrict__ Wk,
    const float* __restrict__ Wv, unsigned short* __restrict__ wTf) {
    const int e8 = blockIdx.x * 256 + threadIdx.x;
    const int lane = e8 & 63;
    const int s = (e8 >> 6) & 31;
    const int n16 = e8 >> 11;        // 0..11
    const int sel = n16 >> 2;
    const float* W = (sel == 0) ? Wq : ((sel == 1) ? Wk : Wv);
    const int h = ((n16 & 3) << 4) + (lane & 15);
    const int cb = s * 32 + ((lane >> 4) << 3);
    s16x8 v;
#pragma unroll
    for (int j = 0; j < 8; ++j) v[j] = (short)f2bf(W[(size_t)(cb + j) * HH + h]);
    *reinterpret_cast<s16x8*>(&wTf[(size_t)e8 * 8]) = v;
}

// ---------------------------------------------------------------------------
// Kernel 1: QKV projection GEMM v14 — anti-convoy: 4 independent blocks/CU.
// 1024 blocks x 4 waves (256 thr); block = 16 rows (HALF an attn tile).
// Wave wn: 16 rows x 48 cols (n16 = 3wn..3wn+2). BK=128, 8 chunks, dbuf LDS
// (8 KB), plain __syncthreads (other resident blocks cover the drain).
// __launch_bounds__(256,4) caps VGPR at 128 -> 4 blocks/CU = 4 de-phased
// barrier domains: some block is always issuing x loads while others MFMA.
// Epilogue: acc -> 6 KB LDS half-tile fragment image -> >=32B-run stores.
// ---------------------------------------------------------------------------
__global__ __launch_bounds__(256, 4) void qkv_kernel(
    const float* __restrict__ x, const unsigned short* __restrict__ wTf,
    unsigned short* __restrict__ Qf, unsigned short* __restrict__ Kf,
    unsigned short* __restrict__ Vf) {
    __shared__ unsigned short xb[2][16 * 128];   // 2 x 4 KB bf16, XOR-swizzled
    const int tid = threadIdx.x;
    const int wn = tid >> 6, lane = tid & 63;
    const int lo = lane & 15, hi = lane >> 4;
    const int rb = blockIdx.x * 16;
    const int mhat = (rb >> 4) & 1;              // which half of the attn tile

    // staging: row = tid>>4 (0..15), 8 f32 at col (tid&15)*8 (chunk-relative)
    const int srow = tid >> 4, sc8 = (tid & 15) * 8;
    const float* xsrc = &x[(size_t)(rb + srow) * CC + sc8];
    const int swz = (srow & 7) << 3;
    const int woff = srow * 128 + (sc8 ^ swz);

    // A-frag read base: row = lo (0..15)
    const int ab0 = lo * 128, as0 = (lo & 7) << 3;

    f32x4 acc[3];
#pragma unroll
    for (int n = 0; n < 3; ++n) acc[n] = (f32x4){0.f, 0.f, 0.f, 0.f};

    // x prefetch, 2 chunks deep (2 sets x 2 f32x4 = 16 VGPR)
    f32x4 pfA[2], pfB[2];
    pfA[0] = *reinterpret_cast<const f32x4*>(xsrc);
    pfA[1] = *reinterpret_cast<const f32x4*>(xsrc + 4);
    pfB[0] = *reinterpret_cast<const f32x4*>(xsrc + 128);
    pfB[1] = *reinterpret_cast<const f32x4*>(xsrc + 128 + 4);

    // B pipeline: 3 reg sets over 32 slots (slot -> set slot%3), 2-ahead
    s16x8 bv[3][3];
#define BLOAD(SET, SLOT)                                                       \
    {                                                                          \
        _Pragma("unroll")                                                      \
        for (int n = 0; n < 3; ++n)                                            \
            bv[SET][n] = *reinterpret_cast<const s16x8*>(                      \
                &wTf[(((size_t)(wn * 3 + n) * 32 + (SLOT)) * 64 + lane) * 8]); \
    }
    BLOAD(0, 0)
    BLOAD(1, 1)

#pragma unroll
    for (int c = 0; c < 8; ++c) {
        // write staged chunk c (one 16B s16x8 per thread)
        {
            const f32x4* pf = (c & 1) ? pfB : pfA;
            s16x8 w;
            w[0] = (short)f2bf(pf[0][0]); w[1] = (short)f2bf(pf[0][1]);
            w[2] = (short)f2bf(pf[0][2]); w[3] = (short)f2bf(pf[0][3]);
            w[4] = (short)f2bf(pf[1][0]); w[5] = (short)f2bf(pf[1][1]);
            w[6] = (short)f2bf(pf[1][2]); w[7] = (short)f2bf(pf[1][3]);
            *reinterpret_cast<s16x8*>(&xb[c & 1][woff]) = w;
        }
        __syncthreads();
        // refill the freed set with chunk c+2
        if (c < 6) {
            if (c & 1) {
                pfB[0] = *reinterpret_cast<const f32x4*>(xsrc + (c + 2) * 128);
                pfB[1] = *reinterpret_cast<const f32x4*>(xsrc + (c + 2) * 128 + 4);
            } else {
                pfA[0] = *reinterpret_cast<const f32x4*>(xsrc + (c + 2) * 128);
                pfA[1] = *reinterpret_cast<const f32x4*>(xsrc + (c + 2) * 128 + 4);
            }
        }
        const unsigned short* base = xb[c & 1];
#pragma unroll
        for (int kh = 0; kh < 4; ++kh) {
            const int slot = c * 4 + kh;
            if (slot + 2 < 32) BLOAD((slot + 2) % 3, slot + 2)
            const s16x8 a = *reinterpret_cast<const s16x8*>(
                &base[ab0 + ((kh * 32 + hi * 8) ^ as0)]);
#pragma unroll
            for (int n = 0; n < 3; ++n)
                acc[n] = __builtin_amdgcn_mfma_f32_16x16x32_bf16(a, bv[slot % 3][n], acc[n], 0, 0, 0);
        }
        // reads of xb[c&1] drain at the next iteration's barrier, which
        // precedes the chunk-c+2 write into this buffer. Safe (v9-proven).
    }
#undef BLOAD

    // ---- Epilogue: acc -> LDS half-tile fragment image -> run stores ----
    __syncthreads();   // mainloop LDS reads done; reuse xb as image (6 KB)
    unsigned short* fr = reinterpret_cast<unsigned short*>(xb);
    // image elems: Q [0,1024) idx=(s*2+half)*128 + tl*8 + j
    //              K [1024,2048) same
    //              V [2048,3072) idx=(mt*2+hf)*256 + h31*8 + jj
#pragma unroll
    for (int n = 0; n < 3; ++n) {
        const int n16 = wn * 3 + n;
        const int sel = n16 >> 2;
#pragma unroll
        for (int r = 0; r < 4; ++r) {
            const int tl = 4 * hi + r;            // local token 0..15
            const unsigned short bvv = f2bf(acc[n][r]);
            if (sel == 0) {
                const int s = n16, half = (lo >> 3) & 1, j = lo & 7;
                fr[(s * 2 + half) * 128 + tl * 8 + j] = bvv;
            } else if (sel == 1) {
                const int s = n16 - 4, half = (lo >> 3) & 1, j = lo & 7;
                fr[1024 + (s * 2 + half) * 128 + tl * 8 + j] = bvv;
            } else {
                const int h = (n16 - 8) * 16 + lo;
                const int mt = h >> 5, h31 = h & 31;
                const int hf = tl >> 3, jj = tl & 7;
                fr[2048 + (mt * 2 + hf) * 256 + h31 * 8 + jj] = bvv;
            }
        }
    }
    __syncthreads();
    // copy out: 384 groups x 8 elems; each group is a 16B store inside a
    // >=32B contiguous global run.
    const int b_ = rb >> 11;
    const int tile = (rb & (TT - 1)) >> 5;
    const size_t tb = ((size_t)b_ * 64 + tile) * 2048;
#pragma unroll
    for (int i = 0; i < 2; ++i) {
        const int g = tid + 256 * i;
        if (g < 384) {
            const s16x8 val = *reinterpret_cast<const s16x8*>(&fr[g * 8]);
            if (g < 256) {
                const int u = g & 127;
                const int s = u >> 5, half = (u >> 4) & 1, t = u & 15;
                unsigned short* dst = (g < 128) ? Qf : Kf;
                *reinterpret_cast<s16x8*>(
                    &dst[tb + (size_t)(s * 64 + half * 32 + mhat * 16 + t) * 8]) = val;
            } else {
                const int u = g - 256;
                const int mt = u >> 6, hf = (u >> 5) & 1, g32 = u & 31;
                *reinterpret_cast<s16x8*>(
                    &Vf[tb + (size_t)((mt * 2 + mhat) * 64 + hf * 32 + g32) * 8]) = val;
            }
        }
    }
}

// ---------------------------------------------------------------------------
// Kernel 2: flash attention (round-7 structure, unchanged — 42.35us build).
// 512 blocks (8 batch x 64 q-tiles of 32 rows) x 8 waves, kv tiles strided.
// ---------------------------------------------------------------------------
__global__ __launch_bounds__(512, 4) void attn_kernel(
    const unsigned short* __restrict__ Qf, const unsigned short* __restrict__ Kf,
    const unsigned short* __restrict__ Vf, float* __restrict__ out) {
    __shared__ __align__(16) char smem[33792 + 2048];   // 35.8 KB
    float (*OfL)[64][33] = reinterpret_cast<float(*)[64][33]>(smem);   // 4 slots
    float (*Mm)[32] = reinterpret_cast<float(*)[32]>(smem + 33792);
    float (*Ml)[32] = reinterpret_cast<float(*)[32]>(smem + 33792 + 1024);

    const int tid = threadIdx.x;
    const int wv = tid >> 6, lane = tid & 63;
    const int q = lane & 31, half = lane >> 5;
    const int b = blockIdx.x & 7;              // batch -> XCD L2 locality
    const int qt = 63 - (blockIdx.x >> 3);     // largest work first
    const int qbase = qt * 32;
    const float CEXP = 0.125f * 1.44269504f;   // scale * log2(e)

    const unsigned short* qp = &Qf[(((size_t)b * 64 + qt) * 256 + lane) * 8];
    s16x8 qf[4];
#pragma unroll
    for (int s = 0; s < 4; ++s) qf[s] = *reinterpret_cast<const s16x8*>(qp + s * 512);

    f32x16 oA, oB;   // O^T h-blocks [0..31],[32..63]; lane holds col q
#pragma unroll
    for (int r = 0; r < 16; ++r) { oA[r] = 0.f; oB[r] = 0.f; }
    float m = -1e30f, l = 0.f;   // raw-score domain

    for (int t = wv; t <= qt; t += 8) {
        const unsigned short* vp = &Vf[(((size_t)b * 64 + t) * 256 + lane) * 8];
        s16x8 vf[4];
#pragma unroll
        for (int i = 0; i < 4; ++i)
            vf[i] = *reinterpret_cast<const s16x8*>(vp + i * 512);
        const unsigned short* kp = &Kf[(((size_t)b * 64 + t) * 256 + lane) * 8];
        f32x16 sa;
#pragma unroll
        for (int r = 0; r < 16; ++r) sa[r] = 0.f;
#pragma unroll
        for (int s = 0; s < 4; ++s) {
            const s16x8 kf = *reinterpret_cast<const s16x8*>(kp + s * 512);
            sa = __builtin_amdgcn_mfma_f32_32x32x16_bf16(kf, qf[s], sa, 0, 0, 0);
        }
        if (t == qt) {
#pragma unroll
            for (int r = 0; r < 16; ++r) {
                const int key = 4 * half + (r & 3) + 8 * (r >> 2);
                if (key > q) sa[r] = -1e30f;
            }
        }
        float pmax = sa[0];
#pragma unroll
        for (int r = 1; r < 16; ++r) pmax = fmaxf(pmax, sa[r]);
        pmax = fmaxf(pmax, __shfl_xor(pmax, 32));
        if (!__all(pmax <= m + 64.f)) {
            const float mnew = fmaxf(m, pmax);
            const float alpha = exp2f((m - mnew) * CEXP);
            l *= alpha;
#pragma unroll
            for (int r = 0; r < 16; ++r) { oA[r] *= alpha; oB[r] *= alpha; }
            m = mnew;
        }
        float rs = 0.f;
#pragma unroll
        for (int r = 0; r < 16; ++r) {
            const float p = exp2f((sa[r] - m) * CEXP);
            sa[r] = p;
            rs += p;
        }
        l += rs + __shfl_xor(rs, 32);
        unsigned d[8];
#pragma unroll
        for (int i = 0; i < 8; ++i) d[i] = cvt_pk_bf16(sa[2 * i], sa[2 * i + 1]);
        const unsigned snd0 = half ? d[0] : d[2];
        const unsigned snd1 = half ? d[1] : d[3];
        const unsigned snd2 = half ? d[4] : d[6];
        const unsigned snd3 = half ? d[5] : d[7];
        const unsigned rcv0 = __shfl_xor(snd0, 32);
        const unsigned rcv1 = __shfl_xor(snd1, 32);
        const unsigned rcv2 = __shfl_xor(snd2, 32);
        const unsigned rcv3 = __shfl_xor(snd3, 32);
        union { unsigned u[4]; s16x8 v; } f0, f1;
        f0.u[0] = half ? rcv0 : d[0];
        f0.u[1] = half ? rcv1 : d[1];
        f0.u[2] = half ? d[2] : rcv0;
        f0.u[3] = half ? d[3] : rcv1;
        f1.u[0] = half ? rcv2 : d[4];
        f1.u[1] = half ? rcv3 : d[5];
        f1.u[2] = half ? d[6] : rcv2;
        f1.u[3] = half ? d[7] : rcv3;
        oA = __builtin_amdgcn_mfma_f32_32x32x16_bf16(vf[0], f0.v, oA, 0, 0, 0);
        oB = __builtin_amdgcn_mfma_f32_32x32x16_bf16(vf[2], f0.v, oB, 0, 0, 0);
        oA = __builtin_amdgcn_mfma_f32_32x32x16_bf16(vf[1], f1.v, oA, 0, 0, 0);
        oB = __builtin_amdgcn_mfma_f32_32x32x16_bf16(vf[3], f1.v, oB, 0, 0, 0);
    }

    // ---- tree combine of 8 partials ----
#define PUBLISH(slot)                                                      \
    {                                                                      \
        _Pragma("unroll")                                                  \
        for (int r = 0; r < 16; ++r) {                                     \
            const int h0 = (r & 3) + 8 * (r >> 2) + 4 * half;              \
            OfL[slot][h0][q] = oA[r];                                      \
            OfL[slot][h0 + 32][q] = oB[r];                                 \
        }                                                                  \
    }
#define MERGE(slot, srcw)                                                  \
    {                                                                      \
        const float mb = Mm[srcw][q], lb = Ml[srcw][q];                    \
        const float M = fmaxf(m, mb);                                      \
        const float wa = exp2f((m - M) * CEXP);                            \
        const float wb = exp2f((mb - M) * CEXP);                           \
        _Pragma("unroll")                                                  \
        for (int r = 0; r < 16; ++r) {                                     \
            const int h0 = (r & 3) + 8 * (r >> 2) + 4 * half;              \
            oA[r] = oA[r] * wa + OfL[slot][h0][q] * wb;                    \
            oB[r] = oB[r] * wa + OfL[slot][h0 + 32][q] * wb;               \
        }                                                                  \
        l = l * wa + lb * wb;                                              \
        m = M;                                                             \
    }

    if (lane < 32) { Mm[wv][q] = m; Ml[wv][q] = l; }
    if (wv >= 4) PUBLISH(wv - 4);
    __syncthreads();
    if (wv < 4) MERGE(wv, wv + 4);
    __syncthreads();
    if (wv == 2 || wv == 3) {
        PUBLISH(wv - 2);
        if (lane < 32) { Mm[wv][q] = m; Ml[wv][q] = l; }
    }
    __syncthreads();
    if (wv < 2) MERGE(wv, wv + 2);
    __syncthreads();
    if (wv == 1) {
        PUBLISH(1);
        if (lane < 32) { Mm[1][q] = m; Ml[1][q] = l; }
    }
    __syncthreads();
    if (wv == 0) {
        MERGE(1, 1);
        const float inv = 1.f / l;
#pragma unroll
        for (int r = 0; r < 16; ++r) {
            const int h0 = (r & 3) + 8 * (r >> 2) + 4 * half;
            OfL[0][h0][q] = oA[r] * inv;
            OfL[0][h0 + 32][q] = oB[r] * inv;
        }
    }
    __syncthreads();
#pragma unroll
    for (int i = 0; i < 4; ++i) {
        const int idx = tid + 512 * i;
        const int h = idx & 63, q2 = idx >> 6;
        out[((size_t)b * TT + qbase + q2) * HH + h] = OfL[0][h][q2];
    }
#undef PUBLISH
#undef MERGE
}

extern "C" void kernel_launch(void* const* d_in, const int* in_sizes, int n_in,
                              void* d_out, int out_size, void* d_ws, size_t ws_size,
                              hipStream_t stream) {
    (void)in_sizes; (void)n_in; (void)out_size; (void)ws_size;
    const float* x  = (const float*)d_in[0];
    const float* Wq = (const float*)d_in[1];
    const float* Wk = (const float*)d_in[2];
    const float* Wv = (const float*)d_in[3];
    float* out = (float*)d_out;

    char* ws = (char*)d_ws;
    unsigned short* wTf = (unsigned short*)ws;                      // 384 KB
    unsigned short* Qf  = (unsigned short*)(ws + 393216);           // 2 MB
    unsigned short* Kf  = (unsigned short*)(ws + 393216 + 2097152); // 2 MB
    unsigned short* Vf  = (unsigned short*)(ws + 393216 + 4194304); // 2 MB

    wt_kernel<<<96, 256, 0, stream>>>(Wq, Wk, Wv, wTf);
    qkv_kernel<<<1024, 256, 0, stream>>>(x, wTf, Qf, Kf, Vf);
    attn_kernel<<<512, 512, 0, stream>>>(Qf, Kf, Vf, out);
}

// Round 19
// 43.975 us; speedup vs baseline: 1.0789x; 1.0789x over previous
//
#include <hip/hip_runtime.h>
#include <hip/hip_bf16.h>

// Problem constants
#define BB 8
#define TT 2048
#define CC 1024
#define HH 64

typedef float f32x4 __attribute__((ext_vector_type(4)));
typedef float f32x16 __attribute__((ext_vector_type(16)));
typedef short s16x8 __attribute__((ext_vector_type(8)));   // 8 bf16 in 4 VGPRs

// fp32 -> bf16 (RNE), pure bit math
static __device__ __forceinline__ unsigned short f2bf(float f) {
    unsigned int u = __float_as_uint(f);
    u = (u + 0x7FFFu + ((u >> 16) & 1u)) >> 16;
    return (unsigned short)u;
}

// pack two f32 -> 2 bf16 in one dword (RNE); dst.lo = src0, dst.hi = src1
static __device__ __forceinline__ unsigned cvt_pk_bf16(float lo, float hi) {
    unsigned r;
    asm("v_cvt_pk_bf16_f32 %0, %1, %2" : "=v"(r) : "v"(lo), "v"(hi));
    return r;
}

// ---------------------------------------------------------------------------
// Kernel 0: pack Wq|Wk|Wv [1024][64] fp32 into MFMA B-fragment order, bf16.
// ---------------------------------------------------------------------------
__global__ __launch_bounds__(256) void wt_kernel(
    const float* __restrict__ Wq, const float* __restrict__ Wk,
    const float* __restrict__ Wv, unsigned short* __restrict__ wTf) {
    const int e8 = blockIdx.x * 256 + threadIdx.x;
    const int lane = e8 & 63;
    const int s = (e8 >> 6) & 31;
    const int n16 = e8 >> 11;        // 0..11
    const int sel = n16 >> 2;
    const float* W = (sel == 0) ? Wq : ((sel == 1) ? Wk : Wv);
    const int h = ((n16 & 3) << 4) + (lane & 15);
    const int cb = s * 32 + ((lane >> 4) << 3);
    s16x8 v;
#pragma unroll
    for (int j = 0; j < 8; ++j) v[j] = (short)f2bf(W[(size_t)(cb + j) * HH + h]);
    *reinterpret_cast<s16x8*>(&wTf[(size_t)e8 * 8]) = v;
}

// ---------------------------------------------------------------------------
// Kernel 1: QKV projection GEMM v15 — ZERO-VMEM mainloop (B-panel in regs).
// 256 blocks x 12 waves (768 thr) = 1 block/CU, one round. Block = 64 rows.
// Wave wn owns ONE n16 (16 cols) x 64 rows (4 M-frags): its entire K=1024
// B-panel = 32 x s16x8 = 128 VGPR, loaded ONCE at start (B-traffic halves
// to 98 MB). Phase 1: stream whole 64x1024 x-tile -> 128 KB LDS (swizzled,
// no barriers) + issue B-panel loads. ONE __syncthreads. Phase 2: 32 K-slots
// of pure ds_read_b128 + MFMA — zero VMEM, zero barriers, latency-proof.
// Epilogue: 2-tile LDS fragment image -> coalesced 16B stores.
// ---------------------------------------------------------------------------
__global__ __launch_bounds__(768, 3) void qkv_kernel(
    const float* __restrict__ x, const unsigned short* __restrict__ wTf,
    unsigned short* __restrict__ Qf, unsigned short* __restrict__ Kf,
    unsigned short* __restrict__ Vf) {
    __shared__ unsigned short xt[64 * 1024];   // 128 KB: whole x-tile, bf16
    const int tid = threadIdx.x;
    const int wn = tid >> 6, lane = tid & 63;  // wn = n16 (0..11)
    const int lo = lane & 15, hi = lane >> 4;
    const int rb = blockIdx.x * 64;

    // ---- B-panel: entire K for this wave's n16, into registers ----
    s16x8 bp[32];
#pragma unroll
    for (int slot = 0; slot < 32; ++slot)
        bp[slot] = *reinterpret_cast<const s16x8*>(
            &wTf[(((size_t)wn * 32 + slot) * 64 + lane) * 8]);

    // ---- Phase 1: stream x tile -> LDS (no barriers) ----
    // granule g (0..8191): row = g>>7, c8 = g&127; 16B bf16 at swizzled slot
#pragma unroll
    for (int i = 0; i < 11; ++i) {
        const int g = tid + 768 * i;
        if (g < 8192) {
            const int row = g >> 7, c8 = g & 127;
            const float* src = &x[(size_t)(rb + row) * CC + c8 * 8];
            const f32x4 f0 = *reinterpret_cast<const f32x4*>(src);
            const f32x4 f1 = *reinterpret_cast<const f32x4*>(src + 4);
            s16x8 w;
            w[0] = (short)f2bf(f0[0]); w[1] = (short)f2bf(f0[1]);
            w[2] = (short)f2bf(f0[2]); w[3] = (short)f2bf(f0[3]);
            w[4] = (short)f2bf(f1[0]); w[5] = (short)f2bf(f1[1]);
            w[6] = (short)f2bf(f1[2]); w[7] = (short)f2bf(f1[3]);
            *reinterpret_cast<s16x8*>(&xt[row * 1024 + ((c8 ^ (row & 7)) * 8)]) = w;
        }
    }
    __syncthreads();   // the ONLY pre-compute barrier

    // ---- Phase 2: 32 K-slots, zero VMEM, zero barriers ----
    f32x4 acc[4];
#pragma unroll
    for (int m = 0; m < 4; ++m) acc[m] = (f32x4){0.f, 0.f, 0.f, 0.f};

    const int sw = lo & 7;
#pragma unroll
    for (int slot = 0; slot < 32; ++slot) {
        const int gr = slot * 4 + hi;   // 16B granule within row
#pragma unroll
        for (int m = 0; m < 4; ++m) {
            const int row = m * 16 + lo;
            const s16x8 a = *reinterpret_cast<const s16x8*>(
                &xt[row * 1024 + ((gr ^ sw) * 8)]);
            acc[m] = __builtin_amdgcn_mfma_f32_16x16x32_bf16(a, bp[slot], acc[m], 0, 0, 0);
        }
    }

    // ---- Epilogue: acc -> 2-tile LDS fragment image -> coalesced stores ----
    __syncthreads();   // all waves' phase-2 reads done; reuse xt as image
    unsigned short* fr = xt;
    // per tile-in-block tib (0/1), base = tib*6144:
    //   Q [0,2048) K [2048,4096) V [4096,6144) elems
    const int sel = wn >> 2;
#pragma unroll
    for (int m = 0; m < 4; ++m) {
        const int tib = m >> 1;
        const int ib = tib * 6144;
#pragma unroll
        for (int r = 0; r < 4; ++r) {
            const int tok31 = (m & 1) * 16 + 4 * hi + r;
            const unsigned short bvv = f2bf(acc[m][r]);
            if (sel == 0) {
                const int s = wn, half = (lo >> 3) & 1, j = lo & 7;
                fr[ib + (s * 64 + half * 32 + tok31) * 8 + j] = bvv;
            } else if (sel == 1) {
                const int s = wn - 4, half = (lo >> 3) & 1, j = lo & 7;
                fr[ib + 2048 + (s * 64 + half * 32 + tok31) * 8 + j] = bvv;
            } else {
                const int h = (wn - 8) * 16 + lo;
                const int mt = h >> 5;
                const int s2 = tok31 >> 4, hf = (tok31 >> 3) & 1, jj = tok31 & 7;
                fr[ib + 4096 + ((mt * 2 + s2) * 64 + hf * 32 + (h & 31)) * 8 + jj] = bvv;
            }
        }
    }
    __syncthreads();
    // copy out: 1536 groups x 8 elems (24 KB), fully coalesced 16B stores
    const int b_ = rb >> 11;
    const int tile0 = (rb & (TT - 1)) >> 5;
#pragma unroll
    for (int i = 0; i < 2; ++i) {
        const int g = tid + 768 * i;            // 0..1535
        const int tib = (g >= 768) ? 1 : 0;
        const int rem = g - tib * 768;
        const int buf = rem >> 8;               // 0=Q 1=K 2=V
        const int off = rem & 255;
        const s16x8 val = *reinterpret_cast<const s16x8*>(
            &fr[tib * 6144 + buf * 2048 + off * 8]);
        unsigned short* dst = (buf == 0) ? Qf : ((buf == 1) ? Kf : Vf);
        *reinterpret_cast<s16x8*>(
            &dst[((size_t)b_ * 64 + tile0 + tib) * 2048 + off * 8]) = val;
    }
}

// ---------------------------------------------------------------------------
// Kernel 2: flash attention (round-7 structure, unchanged — 42.35us build).
// 512 blocks (8 batch x 64 q-tiles of 32 rows) x 8 waves, kv tiles strided.
// ---------------------------------------------------------------------------
__global__ __launch_bounds__(512, 4) void attn_kernel(
    const unsigned short* __restrict__ Qf, const unsigned short* __restrict__ Kf,
    const unsigned short* __restrict__ Vf, float* __restrict__ out) {
    __shared__ __align__(16) char smem[33792 + 2048];   // 35.8 KB
    float (*OfL)[64][33] = reinterpret_cast<float(*)[64][33]>(smem);   // 4 slots
    float (*Mm)[32] = reinterpret_cast<float(*)[32]>(smem + 33792);
    float (*Ml)[32] = reinterpret_cast<float(*)[32]>(smem + 33792 + 1024);

    const int tid = threadIdx.x;
    const int wv = tid >> 6, lane = tid & 63;
    const int q = lane & 31, half = lane >> 5;
    const int b = blockIdx.x & 7;              // batch -> XCD L2 locality
    const int qt = 63 - (blockIdx.x >> 3);     // largest work first
    const int qbase = qt * 32;
    const float CEXP = 0.125f * 1.44269504f;   // scale * log2(e)

    const unsigned short* qp = &Qf[(((size_t)b * 64 + qt) * 256 + lane) * 8];
    s16x8 qf[4];
#pragma unroll
    for (int s = 0; s < 4; ++s) qf[s] = *reinterpret_cast<const s16x8*>(qp + s * 512);

    f32x16 oA, oB;   // O^T h-blocks [0..31],[32..63]; lane holds col q
#pragma unroll
    for (int r = 0; r < 16; ++r) { oA[r] = 0.f; oB[r] = 0.f; }
    float m = -1e30f, l = 0.f;   // raw-score domain

    for (int t = wv; t <= qt; t += 8) {
        const unsigned short* vp = &Vf[(((size_t)b * 64 + t) * 256 + lane) * 8];
        s16x8 vf[4];
#pragma unroll
        for (int i = 0; i < 4; ++i)
            vf[i] = *reinterpret_cast<const s16x8*>(vp + i * 512);
        const unsigned short* kp = &Kf[(((size_t)b * 64 + t) * 256 + lane) * 8];
        f32x16 sa;
#pragma unroll
        for (int r = 0; r < 16; ++r) sa[r] = 0.f;
#pragma unroll
        for (int s = 0; s < 4; ++s) {
            const s16x8 kf = *reinterpret_cast<const s16x8*>(kp + s * 512);
            sa = __builtin_amdgcn_mfma_f32_32x32x16_bf16(kf, qf[s], sa, 0, 0, 0);
        }
        if (t == qt) {
#pragma unroll
            for (int r = 0; r < 16; ++r) {
                const int key = 4 * half + (r & 3) + 8 * (r >> 2);
                if (key > q) sa[r] = -1e30f;
            }
        }
        float pmax = sa[0];
#pragma unroll
        for (int r = 1; r < 16; ++r) pmax = fmaxf(pmax, sa[r]);
        pmax = fmaxf(pmax, __shfl_xor(pmax, 32));
        if (!__all(pmax <= m + 64.f)) {
            const float mnew = fmaxf(m, pmax);
            const float alpha = exp2f((m - mnew) * CEXP);
            l *= alpha;
#pragma unroll
            for (int r = 0; r < 16; ++r) { oA[r] *= alpha; oB[r] *= alpha; }
            m = mnew;
        }
        float rs = 0.f;
#pragma unroll
        for (int r = 0; r < 16; ++r) {
            const float p = exp2f((sa[r] - m) * CEXP);
            sa[r] = p;
            rs += p;
        }
        l += rs + __shfl_xor(rs, 32);
        unsigned d[8];
#pragma unroll
        for (int i = 0; i < 8; ++i) d[i] = cvt_pk_bf16(sa[2 * i], sa[2 * i + 1]);
        const unsigned snd0 = half ? d[0] : d[2];
        const unsigned snd1 = half ? d[1] : d[3];
        const unsigned snd2 = half ? d[4] : d[6];
        const unsigned snd3 = half ? d[5] : d[7];
        const unsigned rcv0 = __shfl_xor(snd0, 32);
        const unsigned rcv1 = __shfl_xor(snd1, 32);
        const unsigned rcv2 = __shfl_xor(snd2, 32);
        const unsigned rcv3 = __shfl_xor(snd3, 32);
        union { unsigned u[4]; s16x8 v; } f0, f1;
        f0.u[0] = half ? rcv0 : d[0];
        f0.u[1] = half ? rcv1 : d[1];
        f0.u[2] = half ? d[2] : rcv0;
        f0.u[3] = half ? d[3] : rcv1;
        f1.u[0] = half ? rcv2 : d[4];
        f1.u[1] = half ? rcv3 : d[5];
        f1.u[2] = half ? d[6] : rcv2;
        f1.u[3] = half ? d[7] : rcv3;
        oA = __builtin_amdgcn_mfma_f32_32x32x16_bf16(vf[0], f0.v, oA, 0, 0, 0);
        oB = __builtin_amdgcn_mfma_f32_32x32x16_bf16(vf[2], f0.v, oB, 0, 0, 0);
        oA = __builtin_amdgcn_mfma_f32_32x32x16_bf16(vf[1], f1.v, oA, 0, 0, 0);
        oB = __builtin_amdgcn_mfma_f32_32x32x16_bf16(vf[3], f1.v, oB, 0, 0, 0);
    }

    // ---- tree combine of 8 partials ----
#define PUBLISH(slot)                                                      \
    {                                                                      \
        _Pragma("unroll")                                                  \
        for (int r = 0; r < 16; ++r) {                                     \
            const int h0 = (r & 3) + 8 * (r >> 2) + 4 * half;              \
            OfL[slot][h0][q] = oA[r];                                      \
            OfL[slot][h0 + 32][q] = oB[r];                                 \
        }                                                                  \
    }
#define MERGE(slot, srcw)                                                  \
    {                                                                      \
        const float mb = Mm[srcw][q], lb = Ml[srcw][q];                    \
        const float M = fmaxf(m, mb);                                      \
        const float wa = exp2f((m - M) * CEXP);                            \
        const float wb = exp2f((mb - M) * CEXP);                           \
        _Pragma("unroll")                                                  \
        for (int r = 0; r < 16; ++r) {                                     \
            const int h0 = (r & 3) + 8 * (r >> 2) + 4 * half;              \
            oA[r] = oA[r] * wa + OfL[slot][h0][q] * wb;                    \
            oB[r] = oB[r] * wa + OfL[slot][h0 + 32][q] * wb;               \
        }                                                                  \
        l = l * wa + lb * wb;                                              \
        m = M;                                                             \
    }

    if (lane < 32) { Mm[wv][q] = m; Ml[wv][q] = l; }
    if (wv >= 4) PUBLISH(wv - 4);
    __syncthreads();
    if (wv < 4) MERGE(wv, wv + 4);
    __syncthreads();
    if (wv == 2 || wv == 3) {
        PUBLISH(wv - 2);
        if (lane < 32) { Mm[wv][q] = m; Ml[wv][q] = l; }
    }
    __syncthreads();
    if (wv < 2) MERGE(wv, wv + 2);
    __syncthreads();
    if (wv == 1) {
        PUBLISH(1);
        if (lane < 32) { Mm[1][q] = m; Ml[1][q] = l; }
    }
    __syncthreads();
    if (wv == 0) {
        MERGE(1, 1);
        const float inv = 1.f / l;
#pragma unroll
        for (int r = 0; r < 16; ++r) {
            const int h0 = (r & 3) + 8 * (r >> 2) + 4 * half;
            OfL[0][h0][q] = oA[r] * inv;
            OfL[0][h0 + 32][q] = oB[r] * inv;
        }
    }
    __syncthreads();
#pragma unroll
    for (int i = 0; i < 4; ++i) {
        const int idx = tid + 512 * i;
        const int h = idx & 63, q2 = idx >> 6;
        out[((size_t)b * TT + qbase + q2) * HH + h] = OfL[0][h][q2];
    }
#undef PUBLISH
#undef MERGE
}

extern "C" void kernel_launch(void* const* d_in, const int* in_sizes, int n_in,
                              void* d_out, int out_size, void* d_ws, size_t ws_size,
                              hipStream_t stream) {
    (void)in_sizes; (void)n_in; (void)out_size; (void)ws_size;
    const float* x  = (const float*)d_in[0];
    const float* Wq = (const float*)d_in[1];
    const float* Wk = (const float*)d_in[2];
    const float* Wv = (const float*)d_in[3];
    float* out = (float*)d_out;

    char* ws = (char*)d_ws;
    unsigned short* wTf = (unsigned short*)ws;                      // 384 KB
    unsigned short* Qf  = (unsigned short*)(ws + 393216);           // 2 MB
    unsigned short* Kf  = (unsigned short*)(ws + 393216 + 2097152); // 2 MB
    unsigned short* Vf  = (unsigned short*)(ws + 393216 + 4194304); // 2 MB

    wt_kernel<<<96, 256, 0, stream>>>(Wq, Wk, Wv, wTf);
    qkv_kernel<<<256, 768, 0, stream>>>(x, wTf, Qf, Kf, Vf);
    attn_kernel<<<512, 512, 0, stream>>>(Qf, Kf, Vf, out);
}